// Round 17
// baseline (78.457 us; speedup 1.0000x reference)
//
#include <hip/hip_runtime.h>
#include <hip/hip_fp16.h>

#define N_NODES 50000
#define N_EDGES 800000
#define F 64
#define NB ((N_NODES + 255) / 256)   // tier-B node-scan blocks
#define NBUCK 391                     // buckets of 128 nodes (dst >> 7)
#define BSHIFT 7
#define BMASK 127
#define BCAP 3072                     // mean 2046, sigma 45 -> +22 sigma
#define P1_BLOCKS ((N_EDGES + 1023) / 1024)   // 782
#define NPB 32                        // nodes per k_agg block (8 waves x 4)

typedef __attribute__((ext_vector_type(2))) float f32x2;

// ---------------------------------------------------------------------------
// GCNConv improved=True. Pipeline (5 kernels):
//   0) init: bcur = 0
//   1) p1c:  FUSED edge binning + xq=fp8(x) convert (3.2MB table, L2-scale).
//            staging lives in d_out (dead until k_agg's final write).
//   2) p2:   per-bucket (128 nodes, 391 blocks): histogram + in-LDS scan ->
//            offsets/counts/dinv.  (dinv must be globally complete before
//            any cross-bucket read -- round-11 race lesson.)
//   3) p3:   counting scatter via LDS cursors -> pack = {fp16(nm)<<16 | src}
//            (nm = dinv[s]*dinv[d]; race-free, runs after p2).
//   4) agg:  8 waves x 4 nodes as 2 interleaved PAIRS. Per pair-iteration:
//            4 GROUP-BROADCAST pack loads (guarded; OOB -> 0 -> nm=0) feed 4
//            independent fp8 row gathers. NO shfls, NO preload phase, NO
//            deg>64 special case (guards handle any deg). fp16-packed sW
//            GEMM, self-loop from xq, relu, log_softmax.
// Aggregate x BEFORE the weight transform ((A x) W == A (x W)).
// ---------------------------------------------------------------------------

union H2U { __half2 h; unsigned u; };

// ---- step 0: bucket cursor init ---------------------------------------------
__global__ void k_init(int* __restrict__ bcur) {
    int t = blockIdx.x * blockDim.x + threadIdx.x;
    if (t < NBUCK) bcur[t] = 0;
}

// ---- step 1: fused bin + fp8 convert ----------------------------------------
__global__ __launch_bounds__(1024) void k_p1c(const int* __restrict__ src,
                                              const int* __restrict__ dst,
                                              int* __restrict__ bcur,
                                              int* __restrict__ staging,
                                              const float4* __restrict__ x4,
                                              unsigned* __restrict__ xq) {
    __shared__ int lcnt[NBUCK];
    __shared__ int lbase[NBUCK];
    int t = threadIdx.x;
    int g = blockIdx.x * 1024 + t;
    if (t < NBUCK) lcnt[t] = 0;
    // convert part (independent of binning; overlaps the LDS-atomic phase)
    if (g < N_NODES * (F / 4)) {          // == N_EDGES == 800000
        float4 v = x4[g];
        unsigned w = 0;
        w = __builtin_amdgcn_cvt_pk_fp8_f32(v.x, v.y, w, false);  // bytes 0,1
        w = __builtin_amdgcn_cvt_pk_fp8_f32(v.z, v.w, w, true);   // bytes 2,3
        xq[g] = w;
    }
    __syncthreads();
    int s = 0, d = 0, bk = 0, rank = 0;
    bool valid = (g < N_EDGES);
    if (valid) {
        s = src[g]; d = dst[g];
        bk = d >> BSHIFT;
        rank = atomicAdd(&lcnt[bk], 1);   // LDS
    }
    __syncthreads();
    if (t < NBUCK && lcnt[t]) lbase[t] = atomicAdd(&bcur[t], lcnt[t]);
    __syncthreads();
    if (valid)
        staging[bk * BCAP + lbase[bk] + rank] = ((d & BMASK) << 16) | s;
}

// ---- step 2: per-bucket histogram + scan -> offsets/counts/dinv --------------
__global__ __launch_bounds__(512) void k_p2(const int* __restrict__ staging,
                                            const int* __restrict__ bcur,
                                            int* __restrict__ offsets,
                                            int* __restrict__ counts,
                                            float* __restrict__ dinv) {
    __shared__ int ncnt[128];
    int t = threadIdx.x;
    int b = blockIdx.x;
    int nb0 = b << BSHIFT;
    if (t < 128) ncnt[t] = 0;
    __syncthreads();
    int beg = b * BCAP, end = beg + bcur[b];
    for (int i = beg + t; i < end; i += 512)
        atomicAdd(&ncnt[staging[i] >> 16], 1);   // LDS
    __syncthreads();
    int c = (t < 128) ? ncnt[t] : 0;
    // inclusive Hillis-Steele scan of ncnt[0..127]
    for (int off = 1; off < 128; off <<= 1) {
        int u = (t < 128 && t >= off) ? ncnt[t - off] : 0;
        __syncthreads();
        if (t < 128) ncnt[t] += u;
        __syncthreads();
    }
    if (t < 128) {
        int node = nb0 + t;
        if (node < N_NODES) {
            offsets[node] = beg + (ncnt[t] - c);  // exclusive prefix + bucket base
            counts[node]  = c;
            dinv[node]    = rsqrtf((float)c + 2.0f);
        }
    }
}

// ---- step 3: counting scatter -> pack = {fp16(norm)<<16 | src} --------------
// Runs strictly after k_p2: dinv[] globally complete -> no cross-WG race.
__global__ __launch_bounds__(512) void k_p3(const int* __restrict__ staging,
                                            const int* __restrict__ bcur,
                                            const int* __restrict__ offsets,
                                            const float* __restrict__ dinv,
                                            unsigned* __restrict__ pack) {
    __shared__ int lcur[128];
    __shared__ float sdinv[128];
    int t = threadIdx.x;
    int b = blockIdx.x;
    int nb0 = b << BSHIFT;
    if (t < 128) {
        int node = nb0 + t;
        lcur[t]  = (node < N_NODES) ? offsets[node] : 0;
        sdinv[t] = (node < N_NODES) ? dinv[node] : 0.f;
    }
    __syncthreads();
    int beg = b * BCAP, end = beg + bcur[b];
    for (int i = beg + t; i < end; i += 512) {
        int v = staging[i];                       // L2-hot re-read
        int dl = v >> 16;                         // node-local dst
        int s  = v & 0xFFFF;
        int pos = atomicAdd(&lcur[dl], 1);        // LDS cursor
        float nm = dinv[s] * sdinv[dl];           // dinv complete (p2 done)
        unsigned hv = (unsigned)__half_as_ushort(__float2half_rn(nm));
        pack[pos] = (hv << 16) | (unsigned)s;     // 4B store, ~12KB window
    }
}

// ---- step 4: aggregate + GEMM + relu + log_softmax --------------------------
// 512 threads = 8 waves; wave handles 4 nodes as 2 interleaved PAIRS.
// qe=lane>>4 picks 1 of 4 parallel edges, qc=lane&15 picks the 4B slice
// (4 packed fp8) of the 64B fp8 row. Pack entries are fetched per-iteration
// as GROUP-BROADCAST loads (16 lanes same address); guards give p=0 for
// lanes past deg -> nm=0, s=0 (harmless row-0 gather). No shfls, no preload,
// handles any deg in one loop.
__global__ __launch_bounds__(512) void k_agg(const unsigned* __restrict__ xq,
                                             const float* __restrict__ dinv,
                                             const int* __restrict__ offsets,
                                             const int* __restrict__ counts,
                                             const unsigned* __restrict__ pack,
                                             const float* __restrict__ W,
                                             const float* __restrict__ bias,
                                             float* __restrict__ out) {
    __shared__ unsigned sWu[F * F / 2];          // pair p -> {W[2p][c], W[2p+1][c]}
    __shared__ float srow[NPB][F];
    int t = threadIdx.x;
    for (int i = t; i < F * F / 2; i += 512) {   // pack W to fp16 pairs
        int p = i >> 6, c = i & 63;
        H2U u;
        u.h = __float22half2_rn(make_float2(W[(2 * p) * F + c], W[(2 * p + 1) * F + c]));
        sWu[i] = u.u;
    }
    __syncthreads();

    int wid = t >> 6, lane = t & 63;
    int qe = lane >> 4, qc = lane & 15;
    int nbase = blockIdx.x * NPB + wid * 4;      // grid 1563; tail guarded

    // ---- vectorized metadata preload (tail reads land in padded slabs) ----
    int4   off4 = *reinterpret_cast<const int4*>(offsets + nbase);
    int4   cnt4 = *reinterpret_cast<const int4*>(counts + nbase);
    float4 dv4  = *reinterpret_cast<const float4*>(dinv + nbase);
    int   begs[4] = { off4.x, off4.y, off4.z, off4.w };
    int   degs[4] = { cnt4.x, cnt4.y, cnt4.z, cnt4.w };
    float dns[4]  = { dv4.x, dv4.y, dv4.z, dv4.w };
#pragma unroll
    for (int i = 0; i < 4; ++i)
        if (nbase + i >= N_NODES) { degs[i] = 0; dns[i] = 0.f; begs[i] = 0; }

    // ---- pairwise-interleaved aggregation, broadcast-pack loads ----
#pragma unroll
    for (int i = 0; i < 4; i += 2) {
        float a00 = 0.f, a01 = 0.f, a02 = 0.f, a03 = 0.f;   // node i
        float a10 = 0.f, a11 = 0.f, a12 = 0.f, a13 = 0.f;   // node i+1
        int dA = degs[i], dB = degs[i + 1];
        int bA = begs[i], bB = begs[i + 1];
        int lim = max(dA, dB);
        for (int r = 0; r < lim; r += 8) {
            int e0 = r + qe, e1 = r + 4 + qe;
            unsigned pA0 = (e0 < dA) ? pack[bA + e0] : 0u;   // broadcast loads
            unsigned pA1 = (e1 < dA) ? pack[bA + e1] : 0u;
            unsigned pB0 = (e0 < dB) ? pack[bB + e0] : 0u;
            unsigned pB1 = (e1 < dB) ? pack[bB + e1] : 0u;
            unsigned qA0 = xq[(size_t)(pA0 & 0xFFFF) * 16 + qc];   // 4 indep gathers
            unsigned qA1 = xq[(size_t)(pA1 & 0xFFFF) * 16 + qc];
            unsigned qB0 = xq[(size_t)(pB0 & 0xFFFF) * 16 + qc];
            unsigned qB1 = xq[(size_t)(pB1 & 0xFFFF) * 16 + qc];
            float mA0 = __half2float(__ushort_as_half((unsigned short)(pA0 >> 16)));
            float mA1 = __half2float(__ushort_as_half((unsigned short)(pA1 >> 16)));
            float mB0 = __half2float(__ushort_as_half((unsigned short)(pB0 >> 16)));
            float mB1 = __half2float(__ushort_as_half((unsigned short)(pB1 >> 16)));
            f32x2 f;
            f = __builtin_amdgcn_cvt_pk_f32_fp8(qA0, false);
            a00 = fmaf(mA0, f.x, a00); a01 = fmaf(mA0, f.y, a01);
            f = __builtin_amdgcn_cvt_pk_f32_fp8(qA0, true);
            a02 = fmaf(mA0, f.x, a02); a03 = fmaf(mA0, f.y, a03);
            f = __builtin_amdgcn_cvt_pk_f32_fp8(qA1, false);
            a00 = fmaf(mA1, f.x, a00); a01 = fmaf(mA1, f.y, a01);
            f = __builtin_amdgcn_cvt_pk_f32_fp8(qA1, true);
            a02 = fmaf(mA1, f.x, a02); a03 = fmaf(mA1, f.y, a03);
            f = __builtin_amdgcn_cvt_pk_f32_fp8(qB0, false);
            a10 = fmaf(mB0, f.x, a10); a11 = fmaf(mB0, f.y, a11);
            f = __builtin_amdgcn_cvt_pk_f32_fp8(qB0, true);
            a12 = fmaf(mB0, f.x, a12); a13 = fmaf(mB0, f.y, a13);
            f = __builtin_amdgcn_cvt_pk_f32_fp8(qB1, false);
            a10 = fmaf(mB1, f.x, a10); a11 = fmaf(mB1, f.y, a11);
            f = __builtin_amdgcn_cvt_pk_f32_fp8(qB1, true);
            a12 = fmaf(mB1, f.x, a12); a13 = fmaf(mB1, f.y, a13);
        }
        // reduce across 4 edge groups (two independent chains interleave)
        a00 += __shfl_xor(a00, 16); a10 += __shfl_xor(a10, 16);
        a01 += __shfl_xor(a01, 16); a11 += __shfl_xor(a11, 16);
        a02 += __shfl_xor(a02, 16); a12 += __shfl_xor(a12, 16);
        a03 += __shfl_xor(a03, 16); a13 += __shfl_xor(a13, 16);
        a00 += __shfl_xor(a00, 32); a10 += __shfl_xor(a10, 32);
        a01 += __shfl_xor(a01, 32); a11 += __shfl_xor(a11, 32);
        a02 += __shfl_xor(a02, 32); a12 += __shfl_xor(a12, 32);
        a03 += __shfl_xor(a03, 32); a13 += __shfl_xor(a13, 32);
        // self loop (weight 2) from fp8 xq; write wave-private srow
        if (qe == 0) {
            int n0 = nbase + i;
            if (n0 < N_NODES) {
                float c2 = 2.0f * dns[i] * dns[i];
                unsigned q = xq[(size_t)n0 * 16 + qc];
                f32x2 f0 = __builtin_amdgcn_cvt_pk_f32_fp8(q, false);
                f32x2 f1 = __builtin_amdgcn_cvt_pk_f32_fp8(q, true);
                float4 w;
                w.x = fmaf(c2, f0.x, a00); w.y = fmaf(c2, f0.y, a01);
                w.z = fmaf(c2, f1.x, a02); w.w = fmaf(c2, f1.y, a03);
                *reinterpret_cast<float4*>(&srow[wid * 4 + i][qc * 4]) = w;
            }
            int n1 = nbase + i + 1;
            if (n1 < N_NODES) {
                float c2 = 2.0f * dns[i + 1] * dns[i + 1];
                unsigned q = xq[(size_t)n1 * 16 + qc];
                f32x2 f0 = __builtin_amdgcn_cvt_pk_f32_fp8(q, false);
                f32x2 f1 = __builtin_amdgcn_cvt_pk_f32_fp8(q, true);
                float4 w;
                w.x = fmaf(c2, f0.x, a10); w.y = fmaf(c2, f0.y, a11);
                w.z = fmaf(c2, f1.x, a12); w.w = fmaf(c2, f1.y, a13);
                *reinterpret_cast<float4*>(&srow[wid * 4 + i + 1][qc * 4]) = w;
            }
        }
    }

    // wave-private srows: no barrier needed, just drain LDS writes
    asm volatile("s_waitcnt lgkmcnt(0)" ::: "memory");

    // ---- 4-node-interleaved GEMM: y[c] = sum_k srow[k] * W[k][c] ----
    float bl = bias[lane];
    float y0 = bl, y1 = bl, y2 = bl, y3 = bl;
#pragma unroll 4
    for (int j = 0; j < 16; ++j) {
        float4 r0 = *reinterpret_cast<const float4*>(&srow[wid * 4 + 0][j * 4]);
        float4 r1 = *reinterpret_cast<const float4*>(&srow[wid * 4 + 1][j * 4]);
        float4 r2 = *reinterpret_cast<const float4*>(&srow[wid * 4 + 2][j * 4]);
        float4 r3 = *reinterpret_cast<const float4*>(&srow[wid * 4 + 3][j * 4]);
        H2U ua, ub;
        ua.u = sWu[(2 * j) * F + lane];
        ub.u = sWu[(2 * j + 1) * F + lane];
        float2 wab = __half22float2(ua.h);
        float2 wcd = __half22float2(ub.h);
        y0 = fmaf(r0.x, wab.x, y0); y0 = fmaf(r0.y, wab.y, y0); y0 = fmaf(r0.z, wcd.x, y0); y0 = fmaf(r0.w, wcd.y, y0);
        y1 = fmaf(r1.x, wab.x, y1); y1 = fmaf(r1.y, wab.y, y1); y1 = fmaf(r1.z, wcd.x, y1); y1 = fmaf(r1.w, wcd.y, y1);
        y2 = fmaf(r2.x, wab.x, y2); y2 = fmaf(r2.y, wab.y, y2); y2 = fmaf(r2.z, wcd.x, y2); y2 = fmaf(r2.w, wcd.y, y2);
        y3 = fmaf(r3.x, wab.x, y3); y3 = fmaf(r3.y, wab.y, y3); y3 = fmaf(r3.z, wcd.x, y3); y3 = fmaf(r3.w, wcd.y, y3);
    }

    float ys[4] = { y0, y1, y2, y3 };
#pragma unroll
    for (int i = 0; i < 4; ++i) {
        float y = fmaxf(ys[i], 0.0f);             // relu
        float mx = y;
#pragma unroll
        for (int off = 32; off > 0; off >>= 1)
            mx = fmaxf(mx, __shfl_xor(mx, off));
        float ex = __expf(y - mx);
        float ss = ex;
#pragma unroll
        for (int off = 32; off > 0; off >>= 1)
            ss += __shfl_xor(ss, off);
        int n = nbase + i;
        if (n < N_NODES) out[n * F + lane] = y - mx - __logf(ss);
    }
}

// ---------------- tier-B fallback (round-3 f32 path) ------------------------

__global__ void k_count_b(const int* __restrict__ dst, int* __restrict__ counts) {
    int e = blockIdx.x * blockDim.x + threadIdx.x;
    if (e < N_EDGES) atomicAdd(&counts[dst[e]], 1);
}
__global__ __launch_bounds__(256) void k_blocksum(const int* __restrict__ counts,
                                                  int* __restrict__ bs) {
    __shared__ int sh[256];
    int t = threadIdx.x;
    int g = blockIdx.x * 256 + t;
    int v = (g < N_NODES) ? counts[g] : 0;
    sh[t] = v;
    __syncthreads();
    for (int off = 128; off > 0; off >>= 1) {
        if (t < off) sh[t] += sh[t + off];
        __syncthreads();
    }
    if (t == 0) bs[blockIdx.x] = sh[0];
}
__global__ __launch_bounds__(256) void k_scanblocks(int* __restrict__ bs) {
    __shared__ int sh[256];
    int t = threadIdx.x;
    int v = (t < NB) ? bs[t] : 0;
    sh[t] = v;
    __syncthreads();
    for (int off = 1; off < 256; off <<= 1) {
        int u = (t >= off) ? sh[t - off] : 0;
        __syncthreads();
        sh[t] += u;
        __syncthreads();
    }
    if (t < NB) bs[t] = sh[t] - v;
}
__global__ __launch_bounds__(256) void k_offsets_b(int* __restrict__ counts,
                                                   const int* __restrict__ bs,
                                                   int* __restrict__ offsets,
                                                   float* __restrict__ dinv) {
    __shared__ int sh[256];
    int t = threadIdx.x;
    int g = blockIdx.x * 256 + t;
    int c = (g < N_NODES) ? counts[g] : 0;
    sh[t] = c;
    __syncthreads();
    for (int off = 1; off < 256; off <<= 1) {
        int u = (t >= off) ? sh[t - off] : 0;
        __syncthreads();
        sh[t] += u;
        __syncthreads();
    }
    int excl = sh[t] - c + bs[blockIdx.x];
    if (g < N_NODES) {
        offsets[g] = excl;
        counts[g]  = excl;
        dinv[g]    = rsqrtf((float)c + 2.0f);
    }
    if (g == 0) offsets[N_NODES] = N_EDGES;
}
__global__ void k_fill_b(const int* __restrict__ src, const int* __restrict__ dst,
                         int* __restrict__ cursor, int* __restrict__ sorted_src) {
    int e = blockIdx.x * blockDim.x + threadIdx.x;
    if (e < N_EDGES) {
        int pos = atomicAdd(&cursor[dst[e]], 1);
        sorted_src[pos] = src[e];
    }
}
__global__ __launch_bounds__(256) void k_agg_b(const float* __restrict__ x,
                                               const float* __restrict__ dinv,
                                               const int* __restrict__ offsets,
                                               const int* __restrict__ sorted_src,
                                               const float* __restrict__ W,
                                               const float* __restrict__ b,
                                               float* __restrict__ out) {
    __shared__ float sW[F * F];
    __shared__ float srow[4][F];
    int t = threadIdx.x;
    for (int i = t; i < F * F; i += 256) sW[i] = W[i];
    int wid = t >> 6, lane = t & 63;
    int n = blockIdx.x * 4 + wid;
    int qe = lane >> 4, qc = lane & 15;
    float dn = dinv[n];
    int beg = offsets[n], end = offsets[n + 1];
    float4 acc = make_float4(0.f, 0.f, 0.f, 0.f);
    for (int base = beg; base < end; base += 4) {
        int e = base + qe;
        int s = n; float nm = 0.f;
        if (e < end) { s = sorted_src[e]; nm = dn * dinv[s]; }
        float4 v = reinterpret_cast<const float4*>(x + (size_t)s * F)[qc];
        acc.x = fmaf(nm, v.x, acc.x); acc.y = fmaf(nm, v.y, acc.y);
        acc.z = fmaf(nm, v.z, acc.z); acc.w = fmaf(nm, v.w, acc.w);
    }
    acc.x += __shfl_xor(acc.x, 16); acc.y += __shfl_xor(acc.y, 16);
    acc.z += __shfl_xor(acc.z, 16); acc.w += __shfl_xor(acc.w, 16);
    acc.x += __shfl_xor(acc.x, 32); acc.y += __shfl_xor(acc.y, 32);
    acc.z += __shfl_xor(acc.z, 32); acc.w += __shfl_xor(acc.w, 32);
    float c2 = 2.0f * dn * dn;
    float4 xv = reinterpret_cast<const float4*>(x + (size_t)n * F)[qc];
    acc.x = fmaf(c2, xv.x, acc.x); acc.y = fmaf(c2, xv.y, acc.y);
    acc.z = fmaf(c2, xv.z, acc.z); acc.w = fmaf(c2, xv.w, acc.w);
    if (qe == 0) reinterpret_cast<float4*>(&srow[wid][0])[qc] = acc;
    __syncthreads();
    float y = b[lane];
#pragma unroll
    for (int k = 0; k < F; ++k) y = fmaf(srow[wid][k], sW[k * F + lane], y);
    y = fmaxf(y, 0.0f);
    float m = y;
#pragma unroll
    for (int off = 32; off > 0; off >>= 1) m = fmaxf(m, __shfl_xor(m, off));
    float ex = __expf(y - m);
    float ss = ex;
#pragma unroll
    for (int off = 32; off > 0; off >>= 1) ss += __shfl_xor(ss, off);
    out[n * F + lane] = y - m - __logf(ss);
}

// ---------------- tier-C fallback (atomic scatter) --------------------------

__global__ void k_init_deg_f(float* __restrict__ deg) {
    int i = blockIdx.x * blockDim.x + threadIdx.x;
    if (i < N_NODES) deg[i] = 2.0f;
}
__global__ void k_count_f(const int* __restrict__ dst, float* __restrict__ deg) {
    int e = blockIdx.x * blockDim.x + threadIdx.x;
    if (e < N_EDGES) atomicAdd(&deg[dst[e]], 1.0f);
}
__global__ void k_dinv_f(float* __restrict__ deg) {
    int i = blockIdx.x * blockDim.x + threadIdx.x;
    if (i < N_NODES) deg[i] = rsqrtf(deg[i]);
}
__global__ void k_selfinit_f(const float* __restrict__ x, const float* __restrict__ dinv,
                             float* __restrict__ agg) {
    int t = blockIdx.x * blockDim.x + threadIdx.x;
    if (t >= N_NODES * (F / 4)) return;
    int n = t >> 4;
    float d = dinv[n];
    float c = 2.0f * d * d;
    float4 v = reinterpret_cast<const float4*>(x)[t];
    float4 o; o.x = c*v.x; o.y = c*v.y; o.z = c*v.z; o.w = c*v.w;
    reinterpret_cast<float4*>(agg)[t] = o;
}
__global__ __launch_bounds__(256) void k_scatter_f(const int* __restrict__ src,
                                                   const int* __restrict__ dst,
                                                   const float* __restrict__ x,
                                                   const float* __restrict__ dinv,
                                                   float* __restrict__ agg) {
    int wave = (blockIdx.x * blockDim.x + threadIdx.x) >> 6;
    int lane = threadIdx.x & 63;
    if (wave >= N_EDGES) return;
    int s = src[wave], d = dst[wave];
    atomicAdd(&agg[d * F + lane], dinv[s] * dinv[d] * x[s * F + lane]);
}
__global__ __launch_bounds__(256) void k_final_f(const float* __restrict__ W,
                                                 const float* __restrict__ b,
                                                 float* __restrict__ out) {
    __shared__ float sW[F * F];
    __shared__ float srow[4][F];
    int t = threadIdx.x;
    for (int i = t; i < F * F; i += 256) sW[i] = W[i];
    int wid = t >> 6, lane = t & 63;
    int n = blockIdx.x * 4 + wid;
    float rv = out[n * F + lane];
    srow[wid][lane] = rv;
    __syncthreads();
    float y = b[lane];
#pragma unroll
    for (int k = 0; k < F; ++k) y = fmaf(srow[wid][k], sW[k * F + lane], y);
    y = fmaxf(y, 0.0f);
    float m = y;
#pragma unroll
    for (int off = 32; off > 0; off >>= 1) m = fmaxf(m, __shfl_xor(m, off));
    float ex = __expf(y - m);
    float ss = ex;
#pragma unroll
    for (int off = 32; off > 0; off >>= 1) ss += __shfl_xor(ss, off);
    out[n * F + lane] = y - m - __logf(ss);
}

// ---------------------------------------------------------------------------

extern "C" void kernel_launch(void* const* d_in, const int* in_sizes, int n_in,
                              void* d_out, int out_size, void* d_ws, size_t ws_size,
                              hipStream_t stream) {
    const float* x    = (const float*)d_in[0];
    const int*   eidx = (const int*)d_in[1];   // [2][E]: row0 = src, row1 = dst
    const float* W    = (const float*)d_in[2];
    const float* b    = (const float*)d_in[3];
    const int* src = eidx;
    const int* dst = eidx + N_EDGES;
    float* out = (float*)d_out;

    // Tier-A13 ws layout (byte offsets):
    //   offsets      [0,        200064)
    //   counts       [200064,   400128)
    //   dinv         [400128,   600192)
    //   bcur         [600192,   601792)   (391 ints, pad)
    //   pack  (u32)  [601792,   5406400)  (391 * 3072 * 4 = 4804608)
    //   xq    (fp8)  [5418112,  8618112)  (800000 uints = 3.2MB)
    // staging (4.8MB int) lives in d_out (12.8MB), dead before k_agg's write.
    const size_t NEED_A13 = 8618112;
    const size_t NEED_B   = 3801040;

    if (ws_size >= NEED_A13) {
        char* ws = (char*)d_ws;
        int*      offsets = (int*)(ws);
        int*      counts  = (int*)(ws + 200064);
        float*    dinv    = (float*)(ws + 400128);
        int*      bcur    = (int*)(ws + 600192);
        unsigned* pack    = (unsigned*)(ws + 601792);
        unsigned* xq      = (unsigned*)(ws + 5418112);
        int*      staging = (int*)d_out;

        k_init<<<1, 512, 0, stream>>>(bcur);
        k_p1c<<<P1_BLOCKS, 1024, 0, stream>>>(src, dst, bcur, staging,
                                              (const float4*)x, xq);
        k_p2<<<NBUCK, 512, 0, stream>>>(staging, bcur, offsets, counts, dinv);
        k_p3<<<NBUCK, 512, 0, stream>>>(staging, bcur, offsets, dinv, pack);
        k_agg<<<(N_NODES + NPB - 1) / NPB, 512, 0, stream>>>(
            xq, dinv, offsets, counts, pack, W, b, out);
    } else if (ws_size >= NEED_B) {
        char* ws = (char*)d_ws;
        int*   counts     = (int*)(ws);
        int*   offsets    = (int*)(ws + 200000);
        float* dinv       = (float*)(ws + 400016);
        int*   bs         = (int*)(ws + 600016);
        int*   sorted_src = (int*)(ws + 601040);

        hipMemsetAsync(counts, 0, N_NODES * sizeof(int), stream);
        k_count_b<<<(N_EDGES + 255) / 256, 256, 0, stream>>>(dst, counts);
        k_blocksum<<<NB, 256, 0, stream>>>(counts, bs);
        k_scanblocks<<<1, 256, 0, stream>>>(bs);
        k_offsets_b<<<NB, 256, 0, stream>>>(counts, bs, offsets, dinv);
        k_fill_b<<<(N_EDGES + 255) / 256, 256, 0, stream>>>(src, dst, counts, sorted_src);
        k_agg_b<<<N_NODES / 4, 256, 0, stream>>>(x, dinv, offsets, sorted_src, W, b, out);
    } else {
        float* deg = (float*)d_ws;
        k_init_deg_f<<<(N_NODES + 255) / 256, 256, 0, stream>>>(deg);
        k_count_f<<<(N_EDGES + 255) / 256, 256, 0, stream>>>(dst, deg);
        k_dinv_f<<<(N_NODES + 255) / 256, 256, 0, stream>>>(deg);
        k_selfinit_f<<<(N_NODES * (F / 4) + 255) / 256, 256, 0, stream>>>(x, deg, out);
        k_scatter_f<<<(N_EDGES * 64 + 255) / 256, 256, 0, stream>>>(src, dst, x, deg, out);
        k_final_f<<<N_NODES / 4, 256, 0, stream>>>(W, b, out);
    }
}

// Round 18
// 74.429 us; speedup vs baseline: 1.0541x; 1.0541x over previous
//
#include <hip/hip_runtime.h>
#include <hip/hip_fp16.h>

#define N_NODES 50000
#define N_EDGES 800000
#define F 64
#define NB ((N_NODES + 255) / 256)   // tier-B node-scan blocks
#define NBUCK 391                     // buckets of 128 nodes (dst >> 7)
#define BSHIFT 7
#define BMASK 127
#define BCAP 3072                     // mean 2046, sigma 45 -> +22 sigma
#define P1_BLOCKS ((N_EDGES + 1023) / 1024)   // 782
#define NPB 32                        // nodes per k_agg block (8 waves x 4)

typedef __attribute__((ext_vector_type(2))) float f32x2;

// ---------------------------------------------------------------------------
// GCNConv improved=True. Round-16 proven configuration (75.2us measured):
//   0) init: bcur = 0
//   1) p1c:  FUSED edge binning + xq=fp8(x) convert (3.2MB table -> L2-scale
//            working set; round-14 fp16 table showed 33MB FETCH = L2 misses).
//   2) p23:  per-bucket (128 nodes, 391 blocks): histogram + in-LDS scan ->
//            offsets/counts/dinv; counting scatter -> pack = src.
//   3) agg:  8 waves x 4 nodes as 2 interleaved PAIRS (round-10 proven body:
//            each load instruction serves 4 rows; 4 loads in flight; shfl
//            distribution from a 64-edge preload). fp16-packed sW GEMM,
//            self-loop from xq, relu, log_softmax.
// Aggregate x BEFORE the weight transform ((A x) W == A (x W)).
// Failed restructurings (do not retry): source dbuf, 4-node unify,
// lane=feature, grid-stride, broadcast-pack+p2/p3 split.
// ---------------------------------------------------------------------------

union H2U { __half2 h; unsigned u; };

// ---- step 0: bucket cursor init ---------------------------------------------
__global__ void k_init(int* __restrict__ bcur) {
    int t = blockIdx.x * blockDim.x + threadIdx.x;
    if (t < NBUCK) bcur[t] = 0;
}

// ---- step 1: fused bin + fp8 convert ----------------------------------------
__global__ __launch_bounds__(1024) void k_p1c(const int* __restrict__ src,
                                              const int* __restrict__ dst,
                                              int* __restrict__ bcur,
                                              int* __restrict__ staging,
                                              const float4* __restrict__ x4,
                                              unsigned* __restrict__ xq) {
    __shared__ int lcnt[NBUCK];
    __shared__ int lbase[NBUCK];
    int t = threadIdx.x;
    int g = blockIdx.x * 1024 + t;
    if (t < NBUCK) lcnt[t] = 0;
    // convert part (independent of binning; overlaps the LDS-atomic phase)
    if (g < N_NODES * (F / 4)) {          // == N_EDGES == 800000
        float4 v = x4[g];
        unsigned w = 0;
        w = __builtin_amdgcn_cvt_pk_fp8_f32(v.x, v.y, w, false);  // bytes 0,1
        w = __builtin_amdgcn_cvt_pk_fp8_f32(v.z, v.w, w, true);   // bytes 2,3
        xq[g] = w;
    }
    __syncthreads();
    int s = 0, d = 0, bk = 0, rank = 0;
    bool valid = (g < N_EDGES);
    if (valid) {
        s = src[g]; d = dst[g];
        bk = d >> BSHIFT;
        rank = atomicAdd(&lcnt[bk], 1);   // LDS
    }
    __syncthreads();
    if (t < NBUCK && lcnt[t]) lbase[t] = atomicAdd(&bcur[t], lcnt[t]);
    __syncthreads();
    if (valid)
        staging[bk * BCAP + lbase[bk] + rank] = ((d & BMASK) << 16) | s;
}

// ---- step 2: per-bucket histogram + LDS scan + counting scatter -------------
__global__ __launch_bounds__(512) void k_p23(const int* __restrict__ staging,
                                             const int* __restrict__ bcur,
                                             int* __restrict__ offsets,
                                             int* __restrict__ counts,
                                             float* __restrict__ dinv,
                                             int* __restrict__ pack) {
    __shared__ int ncnt[128];
    __shared__ int lcur[128];
    int t = threadIdx.x;
    int b = blockIdx.x;
    int nb0 = b << BSHIFT;
    if (t < 128) ncnt[t] = 0;
    __syncthreads();
    int beg = b * BCAP, end = beg + bcur[b];
    for (int i = beg + t; i < end; i += 512)
        atomicAdd(&ncnt[staging[i] >> 16], 1);   // LDS
    __syncthreads();
    int c = (t < 128) ? ncnt[t] : 0;
    // inclusive Hillis-Steele scan of ncnt[0..127]
    for (int off = 1; off < 128; off <<= 1) {
        int u = (t < 128 && t >= off) ? ncnt[t - off] : 0;
        __syncthreads();
        if (t < 128) ncnt[t] += u;
        __syncthreads();
    }
    if (t < 128) {
        int goff = beg + (ncnt[t] - c);          // exclusive prefix + bucket base
        lcur[t] = goff;
        int node = nb0 + t;
        if (node < N_NODES) {
            offsets[node] = goff;
            counts[node]  = c;
            dinv[node]    = rsqrtf((float)c + 2.0f);
        }
    }
    __syncthreads();
    for (int i = beg + t; i < end; i += 512) {
        int v = staging[i];                       // L2-hot re-read
        int pos = atomicAdd(&lcur[v >> 16], 1);   // LDS cursor
        pack[pos] = v & 0xFFFF;                   // src, 4B store, ~12KB window
    }
}

// ---- step 3: aggregate + GEMM + relu + log_softmax --------------------------
// 512 threads = 8 waves; wave handles 4 nodes as 2 interleaved PAIRS.
// qe=lane>>4 picks 1 of 4 parallel edges, qc=lane&15 picks the 4B slice
// (4 packed fp8) of the 64B fp8 row. Lanes >= deg carry nm=0.
__global__ __launch_bounds__(512) void k_agg(const unsigned* __restrict__ xq,
                                             const float* __restrict__ dinv,
                                             const int* __restrict__ offsets,
                                             const int* __restrict__ counts,
                                             const int* __restrict__ pack,
                                             const float* __restrict__ W,
                                             const float* __restrict__ bias,
                                             float* __restrict__ out) {
    __shared__ unsigned sWu[F * F / 2];          // pair p -> {W[2p][c], W[2p+1][c]}
    __shared__ float srow[NPB][F];
    int t = threadIdx.x;
    for (int i = t; i < F * F / 2; i += 512) {   // pack W to fp16 pairs
        int p = i >> 6, c = i & 63;
        H2U u;
        u.h = __float22half2_rn(make_float2(W[(2 * p) * F + c], W[(2 * p + 1) * F + c]));
        sWu[i] = u.u;
    }
    __syncthreads();

    int wid = t >> 6, lane = t & 63;
    int qe = lane >> 4, qc = lane & 15;
    int nbase = blockIdx.x * NPB + wid * 4;      // grid 1563; tail guarded

    // ---- vectorized preload (tail reads land inside the padded slabs) ----
    int4   off4 = *reinterpret_cast<const int4*>(offsets + nbase);
    int4   cnt4 = *reinterpret_cast<const int4*>(counts + nbase);
    float4 dv4  = *reinterpret_cast<const float4*>(dinv + nbase);
    int   begs[4] = { off4.x, off4.y, off4.z, off4.w };
    int   degs[4] = { cnt4.x, cnt4.y, cnt4.z, cnt4.w };
    float dns[4]  = { dv4.x, dv4.y, dv4.z, dv4.w };
#pragma unroll
    for (int i = 0; i < 4; ++i)
        if (nbase + i >= N_NODES) { degs[i] = 0; dns[i] = 0.f; begs[i] = 0; }

    int pls[4]; float nms[4];
#pragma unroll
    for (int i = 0; i < 4; ++i) {
        int s = 0; float nm = 0.f;
        if (lane < degs[i]) {
            s = pack[begs[i] + lane];
            nm = dns[i] * dinv[s];
        }
        pls[i] = s; nms[i] = nm;
    }

    // ---- pairwise-interleaved aggregation (round-10 proven structure) ----
#pragma unroll
    for (int i = 0; i < 4; i += 2) {
        float a00 = 0.f, a01 = 0.f, a02 = 0.f, a03 = 0.f;   // node i
        float a10 = 0.f, a11 = 0.f, a12 = 0.f, a13 = 0.f;   // node i+1
        int lim = min(max(degs[i], degs[i + 1]), 64);
        for (int r = 0; r < lim; r += 8) {
            int e0 = r + qe, e1 = r + 4 + qe;               // <= 63 always
            int   s00 = __shfl(pls[i], e0);     float m00 = __shfl(nms[i], e0);
            int   s01 = __shfl(pls[i], e1);     float m01 = __shfl(nms[i], e1);
            int   s10 = __shfl(pls[i + 1], e0); float m10 = __shfl(nms[i + 1], e0);
            int   s11 = __shfl(pls[i + 1], e1); float m11 = __shfl(nms[i + 1], e1);
            unsigned q00 = xq[(size_t)s00 * 16 + qc];       // 4 indep gathers
            unsigned q01 = xq[(size_t)s01 * 16 + qc];
            unsigned q10 = xq[(size_t)s10 * 16 + qc];
            unsigned q11 = xq[(size_t)s11 * 16 + qc];
            f32x2 f;
            f = __builtin_amdgcn_cvt_pk_f32_fp8(q00, false);
            a00 = fmaf(m00, f.x, a00); a01 = fmaf(m00, f.y, a01);
            f = __builtin_amdgcn_cvt_pk_f32_fp8(q00, true);
            a02 = fmaf(m00, f.x, a02); a03 = fmaf(m00, f.y, a03);
            f = __builtin_amdgcn_cvt_pk_f32_fp8(q01, false);
            a00 = fmaf(m01, f.x, a00); a01 = fmaf(m01, f.y, a01);
            f = __builtin_amdgcn_cvt_pk_f32_fp8(q01, true);
            a02 = fmaf(m01, f.x, a02); a03 = fmaf(m01, f.y, a03);
            f = __builtin_amdgcn_cvt_pk_f32_fp8(q10, false);
            a10 = fmaf(m10, f.x, a10); a11 = fmaf(m10, f.y, a11);
            f = __builtin_amdgcn_cvt_pk_f32_fp8(q10, true);
            a12 = fmaf(m10, f.x, a12); a13 = fmaf(m10, f.y, a13);
            f = __builtin_amdgcn_cvt_pk_f32_fp8(q11, false);
            a10 = fmaf(m11, f.x, a10); a11 = fmaf(m11, f.y, a11);
            f = __builtin_amdgcn_cvt_pk_f32_fp8(q11, true);
            a12 = fmaf(m11, f.x, a12); a13 = fmaf(m11, f.y, a13);
        }
        // ultra-rare overflow (deg > 64), per node, reads pack directly
#pragma unroll
        for (int k = 0; k < 2; ++k) {
            int dend = begs[i + k] + degs[i + k];
            for (int base = begs[i + k] + 64; base < dend; base += 8) {
                int e0o = base + qe, e1o = base + 4 + qe;
                int s0 = 0, s1 = 0; float m0 = 0.f, m1 = 0.f;
                if (e0o < dend) { s0 = pack[e0o]; m0 = dns[i + k] * dinv[s0]; }
                if (e1o < dend) { s1 = pack[e1o]; m1 = dns[i + k] * dinv[s1]; }
                unsigned q0 = xq[(size_t)s0 * 16 + qc];
                unsigned q1 = xq[(size_t)s1 * 16 + qc];
                float* A = (k == 0) ? &a00 : &a10;
                f32x2 f;
                f = __builtin_amdgcn_cvt_pk_f32_fp8(q0, false);
                A[0] = fmaf(m0, f.x, A[0]); A[1] = fmaf(m0, f.y, A[1]);
                f = __builtin_amdgcn_cvt_pk_f32_fp8(q0, true);
                A[2] = fmaf(m0, f.x, A[2]); A[3] = fmaf(m0, f.y, A[3]);
                f = __builtin_amdgcn_cvt_pk_f32_fp8(q1, false);
                A[0] = fmaf(m1, f.x, A[0]); A[1] = fmaf(m1, f.y, A[1]);
                f = __builtin_amdgcn_cvt_pk_f32_fp8(q1, true);
                A[2] = fmaf(m1, f.x, A[2]); A[3] = fmaf(m1, f.y, A[3]);
            }
        }
        // reduce across 4 edge groups (two independent chains interleave)
        a00 += __shfl_xor(a00, 16); a10 += __shfl_xor(a10, 16);
        a01 += __shfl_xor(a01, 16); a11 += __shfl_xor(a11, 16);
        a02 += __shfl_xor(a02, 16); a12 += __shfl_xor(a12, 16);
        a03 += __shfl_xor(a03, 16); a13 += __shfl_xor(a13, 16);
        a00 += __shfl_xor(a00, 32); a10 += __shfl_xor(a10, 32);
        a01 += __shfl_xor(a01, 32); a11 += __shfl_xor(a11, 32);
        a02 += __shfl_xor(a02, 32); a12 += __shfl_xor(a12, 32);
        a03 += __shfl_xor(a03, 32); a13 += __shfl_xor(a13, 32);
        // self loop (weight 2) from fp8 xq; write wave-private srow
        if (qe == 0) {
            int n0 = nbase + i;
            if (n0 < N_NODES) {
                float c2 = 2.0f * dns[i] * dns[i];
                unsigned q = xq[(size_t)n0 * 16 + qc];
                f32x2 f0 = __builtin_amdgcn_cvt_pk_f32_fp8(q, false);
                f32x2 f1 = __builtin_amdgcn_cvt_pk_f32_fp8(q, true);
                float4 w;
                w.x = fmaf(c2, f0.x, a00); w.y = fmaf(c2, f0.y, a01);
                w.z = fmaf(c2, f1.x, a02); w.w = fmaf(c2, f1.y, a03);
                *reinterpret_cast<float4*>(&srow[wid * 4 + i][qc * 4]) = w;
            }
            int n1 = nbase + i + 1;
            if (n1 < N_NODES) {
                float c2 = 2.0f * dns[i + 1] * dns[i + 1];
                unsigned q = xq[(size_t)n1 * 16 + qc];
                f32x2 f0 = __builtin_amdgcn_cvt_pk_f32_fp8(q, false);
                f32x2 f1 = __builtin_amdgcn_cvt_pk_f32_fp8(q, true);
                float4 w;
                w.x = fmaf(c2, f0.x, a10); w.y = fmaf(c2, f0.y, a11);
                w.z = fmaf(c2, f1.x, a12); w.w = fmaf(c2, f1.y, a13);
                *reinterpret_cast<float4*>(&srow[wid * 4 + i + 1][qc * 4]) = w;
            }
        }
    }

    // wave-private srows: no barrier needed, just drain LDS writes
    asm volatile("s_waitcnt lgkmcnt(0)" ::: "memory");

    // ---- 4-node-interleaved GEMM: y[c] = sum_k srow[k] * W[k][c] ----
    float bl = bias[lane];
    float y0 = bl, y1 = bl, y2 = bl, y3 = bl;
#pragma unroll 4
    for (int j = 0; j < 16; ++j) {
        float4 r0 = *reinterpret_cast<const float4*>(&srow[wid * 4 + 0][j * 4]);
        float4 r1 = *reinterpret_cast<const float4*>(&srow[wid * 4 + 1][j * 4]);
        float4 r2 = *reinterpret_cast<const float4*>(&srow[wid * 4 + 2][j * 4]);
        float4 r3 = *reinterpret_cast<const float4*>(&srow[wid * 4 + 3][j * 4]);
        H2U ua, ub;
        ua.u = sWu[(2 * j) * F + lane];
        ub.u = sWu[(2 * j + 1) * F + lane];
        float2 wab = __half22float2(ua.h);
        float2 wcd = __half22float2(ub.h);
        y0 = fmaf(r0.x, wab.x, y0); y0 = fmaf(r0.y, wab.y, y0); y0 = fmaf(r0.z, wcd.x, y0); y0 = fmaf(r0.w, wcd.y, y0);
        y1 = fmaf(r1.x, wab.x, y1); y1 = fmaf(r1.y, wab.y, y1); y1 = fmaf(r1.z, wcd.x, y1); y1 = fmaf(r1.w, wcd.y, y1);
        y2 = fmaf(r2.x, wab.x, y2); y2 = fmaf(r2.y, wab.y, y2); y2 = fmaf(r2.z, wcd.x, y2); y2 = fmaf(r2.w, wcd.y, y2);
        y3 = fmaf(r3.x, wab.x, y3); y3 = fmaf(r3.y, wab.y, y3); y3 = fmaf(r3.z, wcd.x, y3); y3 = fmaf(r3.w, wcd.y, y3);
    }

    float ys[4] = { y0, y1, y2, y3 };
#pragma unroll
    for (int i = 0; i < 4; ++i) {
        float y = fmaxf(ys[i], 0.0f);             // relu
        float mx = y;
#pragma unroll
        for (int off = 32; off > 0; off >>= 1)
            mx = fmaxf(mx, __shfl_xor(mx, off));
        float ex = __expf(y - mx);
        float ss = ex;
#pragma unroll
        for (int off = 32; off > 0; off >>= 1)
            ss += __shfl_xor(ss, off);
        int n = nbase + i;
        if (n < N_NODES) out[n * F + lane] = y - mx - __logf(ss);
    }
}

// ---------------- tier-B fallback (round-3 f32 path) ------------------------

__global__ void k_count_b(const int* __restrict__ dst, int* __restrict__ counts) {
    int e = blockIdx.x * blockDim.x + threadIdx.x;
    if (e < N_EDGES) atomicAdd(&counts[dst[e]], 1);
}
__global__ __launch_bounds__(256) void k_blocksum(const int* __restrict__ counts,
                                                  int* __restrict__ bs) {
    __shared__ int sh[256];
    int t = threadIdx.x;
    int g = blockIdx.x * 256 + t;
    int v = (g < N_NODES) ? counts[g] : 0;
    sh[t] = v;
    __syncthreads();
    for (int off = 128; off > 0; off >>= 1) {
        if (t < off) sh[t] += sh[t + off];
        __syncthreads();
    }
    if (t == 0) bs[blockIdx.x] = sh[0];
}
__global__ __launch_bounds__(256) void k_scanblocks(int* __restrict__ bs) {
    __shared__ int sh[256];
    int t = threadIdx.x;
    int v = (t < NB) ? bs[t] : 0;
    sh[t] = v;
    __syncthreads();
    for (int off = 1; off < 256; off <<= 1) {
        int u = (t >= off) ? sh[t - off] : 0;
        __syncthreads();
        sh[t] += u;
        __syncthreads();
    }
    if (t < NB) bs[t] = sh[t] - v;
}
__global__ __launch_bounds__(256) void k_offsets_b(int* __restrict__ counts,
                                                   const int* __restrict__ bs,
                                                   int* __restrict__ offsets,
                                                   float* __restrict__ dinv) {
    __shared__ int sh[256];
    int t = threadIdx.x;
    int g = blockIdx.x * 256 + t;
    int c = (g < N_NODES) ? counts[g] : 0;
    sh[t] = c;
    __syncthreads();
    for (int off = 1; off < 256; off <<= 1) {
        int u = (t >= off) ? sh[t - off] : 0;
        __syncthreads();
        sh[t] += u;
        __syncthreads();
    }
    int excl = sh[t] - c + bs[blockIdx.x];
    if (g < N_NODES) {
        offsets[g] = excl;
        counts[g]  = excl;
        dinv[g]    = rsqrtf((float)c + 2.0f);
    }
    if (g == 0) offsets[N_NODES] = N_EDGES;
}
__global__ void k_fill_b(const int* __restrict__ src, const int* __restrict__ dst,
                         int* __restrict__ cursor, int* __restrict__ sorted_src) {
    int e = blockIdx.x * blockDim.x + threadIdx.x;
    if (e < N_EDGES) {
        int pos = atomicAdd(&cursor[dst[e]], 1);
        sorted_src[pos] = src[e];
    }
}
__global__ __launch_bounds__(256) void k_agg_b(const float* __restrict__ x,
                                               const float* __restrict__ dinv,
                                               const int* __restrict__ offsets,
                                               const int* __restrict__ sorted_src,
                                               const float* __restrict__ W,
                                               const float* __restrict__ b,
                                               float* __restrict__ out) {
    __shared__ float sW[F * F];
    __shared__ float srow[4][F];
    int t = threadIdx.x;
    for (int i = t; i < F * F; i += 256) sW[i] = W[i];
    int wid = t >> 6, lane = t & 63;
    int n = blockIdx.x * 4 + wid;
    int qe = lane >> 4, qc = lane & 15;
    float dn = dinv[n];
    int beg = offsets[n], end = offsets[n + 1];
    float4 acc = make_float4(0.f, 0.f, 0.f, 0.f);
    for (int base = beg; base < end; base += 4) {
        int e = base + qe;
        int s = n; float nm = 0.f;
        if (e < end) { s = sorted_src[e]; nm = dn * dinv[s]; }
        float4 v = reinterpret_cast<const float4*>(x + (size_t)s * F)[qc];
        acc.x = fmaf(nm, v.x, acc.x); acc.y = fmaf(nm, v.y, acc.y);
        acc.z = fmaf(nm, v.z, acc.z); acc.w = fmaf(nm, v.w, acc.w);
    }
    acc.x += __shfl_xor(acc.x, 16); acc.y += __shfl_xor(acc.y, 16);
    acc.z += __shfl_xor(acc.z, 16); acc.w += __shfl_xor(acc.w, 16);
    acc.x += __shfl_xor(acc.x, 32); acc.y += __shfl_xor(acc.y, 32);
    acc.z += __shfl_xor(acc.z, 32); acc.w += __shfl_xor(acc.w, 32);
    float c2 = 2.0f * dn * dn;
    float4 xv = reinterpret_cast<const float4*>(x + (size_t)n * F)[qc];
    acc.x = fmaf(c2, xv.x, acc.x); acc.y = fmaf(c2, xv.y, acc.y);
    acc.z = fmaf(c2, xv.z, acc.z); acc.w = fmaf(c2, xv.w, acc.w);
    if (qe == 0) reinterpret_cast<float4*>(&srow[wid][0])[qc] = acc;
    __syncthreads();
    float y = b[lane];
#pragma unroll
    for (int k = 0; k < F; ++k) y = fmaf(srow[wid][k], sW[k * F + lane], y);
    y = fmaxf(y, 0.0f);
    float m = y;
#pragma unroll
    for (int off = 32; off > 0; off >>= 1) m = fmaxf(m, __shfl_xor(m, off));
    float ex = __expf(y - m);
    float ss = ex;
#pragma unroll
    for (int off = 32; off > 0; off >>= 1) ss += __shfl_xor(ss, off);
    out[n * F + lane] = y - m - __logf(ss);
}

// ---------------- tier-C fallback (atomic scatter) --------------------------

__global__ void k_init_deg_f(float* __restrict__ deg) {
    int i = blockIdx.x * blockDim.x + threadIdx.x;
    if (i < N_NODES) deg[i] = 2.0f;
}
__global__ void k_count_f(const int* __restrict__ dst, float* __restrict__ deg) {
    int e = blockIdx.x * blockDim.x + threadIdx.x;
    if (e < N_EDGES) atomicAdd(&deg[dst[e]], 1.0f);
}
__global__ void k_dinv_f(float* __restrict__ deg) {
    int i = blockIdx.x * blockDim.x + threadIdx.x;
    if (i < N_NODES) deg[i] = rsqrtf(deg[i]);
}
__global__ void k_selfinit_f(const float* __restrict__ x, const float* __restrict__ dinv,
                             float* __restrict__ agg) {
    int t = blockIdx.x * blockDim.x + threadIdx.x;
    if (t >= N_NODES * (F / 4)) return;
    int n = t >> 4;
    float d = dinv[n];
    float c = 2.0f * d * d;
    float4 v = reinterpret_cast<const float4*>(x)[t];
    float4 o; o.x = c*v.x; o.y = c*v.y; o.z = c*v.z; o.w = c*v.w;
    reinterpret_cast<float4*>(agg)[t] = o;
}
__global__ __launch_bounds__(256) void k_scatter_f(const int* __restrict__ src,
                                                   const int* __restrict__ dst,
                                                   const float* __restrict__ x,
                                                   const float* __restrict__ dinv,
                                                   float* __restrict__ agg) {
    int wave = (blockIdx.x * blockDim.x + threadIdx.x) >> 6;
    int lane = threadIdx.x & 63;
    if (wave >= N_EDGES) return;
    int s = src[wave], d = dst[wave];
    atomicAdd(&agg[d * F + lane], dinv[s] * dinv[d] * x[s * F + lane]);
}
__global__ __launch_bounds__(256) void k_final_f(const float* __restrict__ W,
                                                 const float* __restrict__ b,
                                                 float* __restrict__ out) {
    __shared__ float sW[F * F];
    __shared__ float srow[4][F];
    int t = threadIdx.x;
    for (int i = t; i < F * F; i += 256) sW[i] = W[i];
    int wid = t >> 6, lane = t & 63;
    int n = blockIdx.x * 4 + wid;
    float rv = out[n * F + lane];
    srow[wid][lane] = rv;
    __syncthreads();
    float y = b[lane];
#pragma unroll
    for (int k = 0; k < F; ++k) y = fmaf(srow[wid][k], sW[k * F + lane], y);
    y = fmaxf(y, 0.0f);
    float m = y;
#pragma unroll
    for (int off = 32; off > 0; off >>= 1) m = fmaxf(m, __shfl_xor(m, off));
    float ex = __expf(y - m);
    float ss = ex;
#pragma unroll
    for (int off = 32; off > 0; off >>= 1) ss += __shfl_xor(ss, off);
    out[n * F + lane] = y - m - __logf(ss);
}

// ---------------------------------------------------------------------------

extern "C" void kernel_launch(void* const* d_in, const int* in_sizes, int n_in,
                              void* d_out, int out_size, void* d_ws, size_t ws_size,
                              hipStream_t stream) {
    const float* x    = (const float*)d_in[0];
    const int*   eidx = (const int*)d_in[1];   // [2][E]: row0 = src, row1 = dst
    const float* W    = (const float*)d_in[2];
    const float* b    = (const float*)d_in[3];
    const int* src = eidx;
    const int* dst = eidx + N_EDGES;
    float* out = (float*)d_out;

    // Tier-A12 ws layout (byte offsets):
    //   offsets      [0,        200064)
    //   counts       [200064,   400128)
    //   dinv         [400128,   600192)
    //   bcur         [600192,   601792)   (391 ints, pad)
    //   pack  (int)  [601792,   5406400)  (391 * 3072 * 4 = 4804608)
    //   xq    (fp8)  [5418112,  8618112)  (800000 uints = 3.2MB, L2-resident)
    // staging (4.8MB int) lives in d_out (12.8MB), dead before k_agg's write.
    const size_t NEED_A12 = 8618112;
    const size_t NEED_B   = 3801040;

    if (ws_size >= NEED_A12) {
        char* ws = (char*)d_ws;
        int*      offsets = (int*)(ws);
        int*      counts  = (int*)(ws + 200064);
        float*    dinv    = (float*)(ws + 400128);
        int*      bcur    = (int*)(ws + 600192);
        int*      pack    = (int*)(ws + 601792);
        unsigned* xq      = (unsigned*)(ws + 5418112);
        int*      staging = (int*)d_out;

        k_init<<<1, 512, 0, stream>>>(bcur);
        k_p1c<<<P1_BLOCKS, 1024, 0, stream>>>(src, dst, bcur, staging,
                                              (const float4*)x, xq);
        k_p23<<<NBUCK, 512, 0, stream>>>(staging, bcur, offsets, counts, dinv, pack);
        k_agg<<<(N_NODES + NPB - 1) / NPB, 512, 0, stream>>>(
            xq, dinv, offsets, counts, pack, W, b, out);
    } else if (ws_size >= NEED_B) {
        char* ws = (char*)d_ws;
        int*   counts     = (int*)(ws);
        int*   offsets    = (int*)(ws + 200000);
        float* dinv       = (float*)(ws + 400016);
        int*   bs         = (int*)(ws + 600016);
        int*   sorted_src = (int*)(ws + 601040);

        hipMemsetAsync(counts, 0, N_NODES * sizeof(int), stream);
        k_count_b<<<(N_EDGES + 255) / 256, 256, 0, stream>>>(dst, counts);
        k_blocksum<<<NB, 256, 0, stream>>>(counts, bs);
        k_scanblocks<<<1, 256, 0, stream>>>(bs);
        k_offsets_b<<<NB, 256, 0, stream>>>(counts, bs, offsets, dinv);
        k_fill_b<<<(N_EDGES + 255) / 256, 256, 0, stream>>>(src, dst, counts, sorted_src);
        k_agg_b<<<N_NODES / 4, 256, 0, stream>>>(x, dinv, offsets, sorted_src, W, b, out);
    } else {
        float* deg = (float*)d_ws;
        k_init_deg_f<<<(N_NODES + 255) / 256, 256, 0, stream>>>(deg);
        k_count_f<<<(N_EDGES + 255) / 256, 256, 0, stream>>>(dst, deg);
        k_dinv_f<<<(N_NODES + 255) / 256, 256, 0, stream>>>(deg);
        k_selfinit_f<<<(N_NODES * (F / 4) + 255) / 256, 256, 0, stream>>>(x, deg, out);
        k_scatter_f<<<(N_EDGES * 64 + 255) / 256, 256, 0, stream>>>(src, dst, x, deg, out);
        k_final_f<<<N_NODES / 4, 256, 0, stream>>>(W, b, out);
    }
}